// Round 6
// baseline (786.879 us; speedup 1.0000x reference)
//
#include <hip/hip_runtime.h>
#include <stdint.h>

#define B_ 8
#define N_ 2048
#define D_ 1024
#define E_ 8
#define F_ 4096
#define H_ 1024
#define T_ (B_*N_)

typedef unsigned short u16;
typedef unsigned int u32;
typedef __attribute__((ext_vector_type(8))) short short8;
typedef __attribute__((ext_vector_type(4))) float f32x4;

#define AS1 __attribute__((address_space(1)))
#define AS3 __attribute__((address_space(3)))

__device__ __forceinline__ void gll16(const void* g, void* l) {
  __builtin_amdgcn_global_load_lds((AS1 const void*)g, (AS3 void*)l, 16, 0, 0);
}

__device__ __forceinline__ u16 f2bf(float f) {
  u32 u = __float_as_uint(f);
  u32 r = (u + 0x7fffu + ((u >> 16) & 1u)) >> 16;
  return (u16)r;
}

// ---------- convert x fp32 -> bf16 ----------
__global__ void cvt_x(const float* __restrict__ x, u16* __restrict__ xb) {
  int i = blockIdx.x * blockDim.x + threadIdx.x;
  const int total = T_ * D_ / 8;
  for (; i < total; i += gridDim.x * blockDim.x) {
    float4 v0 = ((const float4*)x)[2*i];
    float4 v1 = ((const float4*)x)[2*i+1];
    uint4 o;
    o.x = (u32)f2bf(v0.x) | ((u32)f2bf(v0.y) << 16);
    o.y = (u32)f2bf(v0.z) | ((u32)f2bf(v0.w) << 16);
    o.z = (u32)f2bf(v1.x) | ((u32)f2bf(v1.y) << 16);
    o.w = (u32)f2bf(v1.z) | ((u32)f2bf(v1.w) << 16);
    ((uint4*)xb)[i] = o;
  }
}

// ---------- convert + transpose W1[e][d][f] -> w1t[e][f][d] bf16 ----------
__global__ void cvt_w1(const float* __restrict__ W1, u16* __restrict__ w1t) {
  __shared__ float tile[64][65];
  int e = blockIdx.z;
  int d0 = blockIdx.y * 64, f0 = blockIdx.x * 64;
  int tid = threadIdx.x;
  int r = tid >> 2, cs = (tid & 3) * 16;
  const float* src = W1 + ((size_t)e * D_ + d0) * F_ + f0;
  #pragma unroll
  for (int j = 0; j < 4; ++j) {
    float4 v = *(const float4*)&src[(size_t)r * F_ + cs + j*4];
    tile[r][cs + j*4 + 0] = v.x;
    tile[r][cs + j*4 + 1] = v.y;
    tile[r][cs + j*4 + 2] = v.z;
    tile[r][cs + j*4 + 3] = v.w;
  }
  __syncthreads();
  u32 vals[8];
  #pragma unroll
  for (int j = 0; j < 8; ++j) {
    u32 lo = f2bf(tile[cs + 2*j][r]);
    u32 hi = f2bf(tile[cs + 2*j + 1][r]);
    vals[j] = lo | (hi << 16);
  }
  uint4 A = {vals[0], vals[1], vals[2], vals[3]};
  uint4 Bv = {vals[4], vals[5], vals[6], vals[7]};
  uint4* dst = (uint4*)(w1t + ((size_t)e * F_ + f0 + r) * D_ + d0 + cs);
  dst[0] = A;
  dst[1] = Bv;
}

// ---------- router: fp32 logits, top-2, softmax -> dense gates [T][E] ----------
__global__ void router(const float* __restrict__ x, const float* __restrict__ Wg,
                       const float* __restrict__ bg, float* __restrict__ gdense) {
  int wave = (blockIdx.x * blockDim.x + threadIdx.x) >> 6;
  int lane = threadIdx.x & 63;
  if (wave >= T_) return;
  const float* xr = x + (size_t)wave * D_;
  float acc[8] = {0,0,0,0,0,0,0,0};
  for (int i = 0; i < D_/64; ++i) {
    int d = i*64 + lane;
    float xv = xr[d];
    const float4* wr = (const float4*)(Wg + (size_t)d * E_);
    float4 wa = wr[0], wb2 = wr[1];
    acc[0] += xv * wa.x;  acc[1] += xv * wa.y;
    acc[2] += xv * wa.z;  acc[3] += xv * wa.w;
    acc[4] += xv * wb2.x; acc[5] += xv * wb2.y;
    acc[6] += xv * wb2.z; acc[7] += xv * wb2.w;
  }
  #pragma unroll
  for (int e = 0; e < 8; ++e) {
    #pragma unroll
    for (int s = 32; s > 0; s >>= 1) acc[e] += __shfl_xor(acc[e], s);
  }
  if (lane == 0) {
    float v[8];
    #pragma unroll
    for (int e = 0; e < 8; ++e) v[e] = acc[e] + bg[e];
    int i1 = -1, i2 = -1;
    float b1v = -1e30f, b2v = -1e30f;
    #pragma unroll
    for (int e = 0; e < 8; ++e) {
      float vv = v[e];
      if (vv > b1v) { b2v = b1v; i2 = i1; b1v = vv; i1 = e; }
      else if (vv > b2v) { b2v = vv; i2 = e; }
    }
    float e2 = __expf(b2v - b1v);
    float inv = 1.f / (1.f + e2);
    float* gr = gdense + (size_t)wave * E_;
    #pragma unroll
    for (int e = 0; e < 8; ++e) gr[e] = 0.f;
    gr[i1] = inv;
    gr[i2] = e2 * inv;
  }
}

// ---------- compaction: per (b,e) ordered token list, padded to FULL N_ ----------
__global__ void compact(const float* __restrict__ gdense, int* __restrict__ lists,
                        float* __restrict__ glist, int* __restrict__ cntp,
                        float* __restrict__ G) {
  int be = blockIdx.x;
  int b = be >> 3, e = be & 7;
  __shared__ int warp_off[4];
  __shared__ float wsum[4];
  int tid = threadIdx.x;
  int lane = tid & 63, w = tid >> 6;
  int base = 0;
  float gsum = 0.f;
  for (int c = 0; c < N_; c += 256) {
    int t = b * N_ + c + tid;
    float g = gdense[(size_t)t * E_ + e];
    gsum += g;
    bool sel = g > 0.f;
    unsigned long long m = __ballot(sel);
    int my = __popcll(m & ((1ull << lane) - 1ull));
    int wcnt = __popcll(m);
    if (lane == 0) warp_off[w] = wcnt;
    __syncthreads();
    int off = 0;
    for (int i = 0; i < w; ++i) off += warp_off[i];
    int tot = warp_off[0] + warp_off[1] + warp_off[2] + warp_off[3];
    if (sel) {
      int pos = base + off + my;
      lists[be * N_ + pos] = t;
      glist[be * N_ + pos] = g;
    }
    base += tot;
    __syncthreads();
  }
  // pad with dummy token (gate 0) to FULL N_ so gemm1 can bulk-preload safely
  for (int p = base + tid; p < N_; p += 256) {
    lists[be * N_ + p] = b * N_;
    glist[be * N_ + p] = 0.f;
  }
  if (tid == 0) cntp[be] = (base + 127) & ~127;
  #pragma unroll
  for (int s = 32; s > 0; s >>= 1) gsum += __shfl_xor(gsum, s);
  if (lane == 0) wsum[w] = gsum;
  __syncthreads();
  if (tid == 0) G[be] = wsum[0] + wsum[1] + wsum[2] + wsum[3];
}

// ---------- out init with bias-2 term: out[b][h] = sum_e G[b,e]*b2[e][h] ----------
__global__ void init_out(const float* __restrict__ G, const float* __restrict__ b2,
                         float* __restrict__ out) {
  int i = blockIdx.x * 256 + threadIdx.x;
  int b = i >> 10, h = i & 1023;
  float acc = 0.f;
  #pragma unroll
  for (int e = 0; e < 8; ++e) acc += G[b * E_ + e] * b2[e * H_ + h];
  out[i] = acc;
}

// ---------- GEMM1: m97-shape 2-phase, 36KB LDS -> 4 blocks/CU ----------
// Block = (e, b, ftile128); e-major XCD swizzle (bid%8 == e). Chunk loop inside,
// continuous staging across chunks, single __syncthreads per k-step (compiler
// waits). Plain store (exclusive ownership), gates read as float4 in epilogue.
__launch_bounds__(256, 4)
__global__ void gemm1(const u16* __restrict__ xb, const u16* __restrict__ w1t,
                      const float* __restrict__ b1, const int* __restrict__ lists,
                      const float* __restrict__ glist, const int* __restrict__ cntp,
                      float* __restrict__ sbuf) {
  int bid = blockIdx.x;
  int e  = bid & 7;           // XCD id == expert
  int r  = bid >> 3;          // 0..255
  int b  = r >> 5;            // 0..7
  int ft = r & 31;            // 0..31
  int be = b * 8 + e;
  int fbase = ft * 128;
  int nchunks = cntp[be] >> 7;
  if (nchunks == 0) return;   // sbuf memset covers

  __shared__ u16 sA[2][4096];   // 8 KB each: [kc4][row128] of short8
  __shared__ u16 sB[2][4096];
  __shared__ u16 sTok[2048];    // token ids (< 16384 fits u16); aliased as reduce scratch

  int tid  = threadIdx.x;
  int lane = tid & 63;
  int w    = tid >> 6;
  int wm   = w >> 1, wn = w & 1;
  int row  = tid & 127;
  int koff = (tid >> 7) * 8;
  int wb   = w << 9;            // wave-uniform LDS element base
  int fr   = lane & 15;
  int kq   = lane >> 4;

  // one-time preload of token ids (lists padded to N_ by compact)
  for (int i = tid; i < 2048; i += 256)
    sTok[i] = (u16)lists[be * N_ + i];

  float b1f[4];
  #pragma unroll
  for (int ni = 0; ni < 4; ++ni)
    b1f[ni] = b1[e * F_ + fbase + wn * 64 + ni * 16 + fr];
  asm volatile("" : "+v"(b1f[0]), "+v"(b1f[1]), "+v"(b1f[2]), "+v"(b1f[3]));
  __syncthreads();   // sTok visible

  const u16* bSrc = w1t + ((size_t)(e * F_ + fbase + row)) * D_ + koff;
  const float* gRow = glist + be * N_;

  f32x4 acc[4][4];
  #pragma unroll
  for (int i = 0; i < 4; ++i)
    #pragma unroll
    for (int j = 0; j < 4; ++j) acc[i][j] = (f32x4){0.f, 0.f, 0.f, 0.f};
  float osum[4] = {0.f, 0.f, 0.f, 0.f};

  const int S = nchunks * 32;   // global k-steps
  int tokA = (int)sTok[row];    // staging token for chunk 0

#define STAGE(s_, buf_) do { \
    int kk_ = (s_) & 31; \
    if (kk_ == 0 && (s_) > 0) tokA = (int)sTok[((s_) >> 5) * 128 + row]; \
    const u16* aS_ = xb + (size_t)tokA * D_ + kk_ * 32 + koff; \
    const u16* bS_ = bSrc + kk_ * 32; \
    gll16(aS_,      &sA[buf_][wb]); \
    gll16(aS_ + 16, &sA[buf_][2048 + wb]); \
    gll16(bS_,      &sB[buf_][wb]); \
    gll16(bS_ + 16, &sB[buf_][2048 + wb]); \
  } while (0)

  STAGE(0, 0);
  int buf = 0;

  for (int s = 0; s < S; ++s) {
    __syncthreads();            // stage(s) landed (implicit vmcnt/lgkm drain)
    if (s + 1 < S) STAGE(s + 1, buf ^ 1);

    const short8* Ab = (const short8*)&sA[buf][0];
    const short8* Bb = (const short8*)&sB[buf][0];
    short8 a[4], bfr[4];
    #pragma unroll
    for (int mi = 0; mi < 4; ++mi) a[mi] = Ab[kq * 128 + wm * 64 + mi * 16 + fr];
    #pragma unroll
    for (int ni = 0; ni < 4; ++ni) bfr[ni] = Bb[kq * 128 + wn * 64 + ni * 16 + fr];
    #pragma unroll
    for (int mi = 0; mi < 4; ++mi)
      #pragma unroll
      for (int ni = 0; ni < 4; ++ni)
        acc[mi][ni] = __builtin_amdgcn_mfma_f32_16x16x32_bf16(a[mi], bfr[ni], acc[mi][ni], 0, 0, 0);

    if ((s & 31) == 31) {
      // chunk epilogue: relu(acc+b1)*gate, gate rows via contiguous float4
      int c = s >> 5;
      float4 g[4];
      #pragma unroll
      for (int mi = 0; mi < 4; ++mi)
        g[mi] = *(const float4*)&gRow[c * 128 + wm * 64 + mi * 16 + kq * 4];
      #pragma unroll
      for (int ni = 0; ni < 4; ++ni) {
        float sum = 0.f;
        #pragma unroll
        for (int mi = 0; mi < 4; ++mi) {
          sum += fmaxf(acc[mi][ni][0] + b1f[ni], 0.f) * g[mi].x;
          sum += fmaxf(acc[mi][ni][1] + b1f[ni], 0.f) * g[mi].y;
          sum += fmaxf(acc[mi][ni][2] + b1f[ni], 0.f) * g[mi].z;
          sum += fmaxf(acc[mi][ni][3] + b1f[ni], 0.f) * g[mi].w;
        }
        osum[ni] += sum;
      }
      #pragma unroll
      for (int i = 0; i < 4; ++i)
        #pragma unroll
        for (int j = 0; j < 4; ++j) acc[i][j] = (f32x4){0.f, 0.f, 0.f, 0.f};
    }
    buf ^= 1;
  }
#undef STAGE

  // final reduce: across kq groups (lanes), then across wm waves via LDS
  #pragma unroll
  for (int ni = 0; ni < 4; ++ni) {
    osum[ni] += __shfl_xor(osum[ni], 16);
    osum[ni] += __shfl_xor(osum[ni], 32);
  }
  float* sRed = (float*)sTok;   // alias: tokens no longer needed
  __syncthreads();
  if (wm == 0 && lane < 16) {
    #pragma unroll
    for (int ni = 0; ni < 4; ++ni)
      sRed[wn * 64 + ni * 16 + lane] = osum[ni];
  }
  __syncthreads();
  if (wm == 1 && lane < 16) {
    #pragma unroll
    for (int ni = 0; ni < 4; ++ni) {
      int fc = wn * 64 + ni * 16 + lane;
      sbuf[(size_t)be * F_ + fbase + fc] = sRed[fc] + osum[ni];
    }
  }
}

// ---------- GEMM2: out[b][h] += sum_f s[b,e,f] * W2[e][f][h] (memory-bound) ----------
__global__ void gemm2(const float* __restrict__ sbuf, const float* __restrict__ W2,
                      float* __restrict__ out) {
  int fc = blockIdx.x;   // 16 chunks of 256 f
  int ht = blockIdx.y;   // 4 tiles of 256 h
  int e  = blockIdx.z;   // 8 experts
  __shared__ float sS[8][256];
  int tid = threadIdx.x;
  #pragma unroll
  for (int b = 0; b < 8; ++b)
    sS[b][tid] = sbuf[((size_t)(b * E_ + e)) * F_ + fc * 256 + tid];
  __syncthreads();
  int h = ht * 256 + tid;
  float acc[8] = {0,0,0,0,0,0,0,0};
  const float* w2p = W2 + (size_t)e * F_ * H_ + (size_t)(fc * 256) * H_ + h;
  for (int f = 0; f < 256; ++f) {
    float wv = w2p[(size_t)f * H_];
    #pragma unroll
    for (int b = 0; b < 8; ++b) acc[b] += sS[b][f] * wv;
  }
  #pragma unroll
  for (int b = 0; b < 8; ++b) atomicAdd(&out[b * H_ + h], acc[b]);
}

extern "C" void kernel_launch(void* const* d_in, const int* in_sizes, int n_in,
                              void* d_out, int out_size, void* d_ws, size_t ws_size,
                              hipStream_t stream) {
  const float* x  = (const float*)d_in[0];
  const float* Wg = (const float*)d_in[1];
  const float* bg = (const float*)d_in[2];
  const float* W1 = (const float*)d_in[3];
  const float* b1 = (const float*)d_in[4];
  const float* W2 = (const float*)d_in[5];
  const float* b2 = (const float*)d_in[6];
  float* out = (float*)d_out;

  char* ws = (char*)d_ws;
  u16*   xb     = (u16*)(ws);
  u16*   w1t    = (u16*)(ws + 33554432);
  float* gdense = (float*)(ws + 100663296);
  int*   lists  = (int*)(ws + 101187584);
  float* glist  = (float*)(ws + 101711872);
  int*   cntp   = (int*)(ws + 102236160);
  float* G      = (float*)(ws + 102236416);
  float* sbuf   = (float*)(ws + 102236672);

  hipMemsetAsync(sbuf, 0, (size_t)64 * F_ * sizeof(float), stream);
  cvt_x<<<8192, 256, 0, stream>>>(x, xb);
  cvt_w1<<<dim3(F_/64, D_/64, E_), 256, 0, stream>>>(W1, w1t);
  router<<<T_/4, 256, 0, stream>>>(x, Wg, bg, gdense);
  compact<<<64, 256, 0, stream>>>(gdense, lists, glist, cntp, G);
  init_out<<<(B_*H_)/256, 256, 0, stream>>>(G, b2, out);
  gemm1<<<2048, 256, 0, stream>>>(xb, w1t, b1, lists, glist, cntp, sbuf);
  gemm2<<<dim3(16, 4, 8), 256, 0, stream>>>(sbuf, W2, out);
}

// Round 7
// 593.670 us; speedup vs baseline: 1.3254x; 1.3254x over previous
//
#include <hip/hip_runtime.h>
#include <stdint.h>

#define B_ 8
#define N_ 2048
#define D_ 1024
#define E_ 8
#define F_ 4096
#define H_ 1024
#define T_ (B_*N_)

typedef unsigned short u16;
typedef unsigned int u32;
typedef __attribute__((ext_vector_type(8))) short short8;
typedef __attribute__((ext_vector_type(4))) float f32x4;

#define AS1 __attribute__((address_space(1)))
#define AS3 __attribute__((address_space(3)))

__device__ __forceinline__ void gll16(const void* g, void* l) {
  __builtin_amdgcn_global_load_lds((AS1 const void*)g, (AS3 void*)l, 16, 0, 0);
}

__device__ __forceinline__ u16 f2bf(float f) {
  u32 u = __float_as_uint(f);
  u32 r = (u + 0x7fffu + ((u >> 16) & 1u)) >> 16;
  return (u16)r;
}

// ---------- convert x fp32 -> bf16 ----------
__global__ void cvt_x(const float* __restrict__ x, u16* __restrict__ xb) {
  int i = blockIdx.x * blockDim.x + threadIdx.x;
  const int total = T_ * D_ / 8;
  for (; i < total; i += gridDim.x * blockDim.x) {
    float4 v0 = ((const float4*)x)[2*i];
    float4 v1 = ((const float4*)x)[2*i+1];
    uint4 o;
    o.x = (u32)f2bf(v0.x) | ((u32)f2bf(v0.y) << 16);
    o.y = (u32)f2bf(v0.z) | ((u32)f2bf(v0.w) << 16);
    o.z = (u32)f2bf(v1.x) | ((u32)f2bf(v1.y) << 16);
    o.w = (u32)f2bf(v1.z) | ((u32)f2bf(v1.w) << 16);
    ((uint4*)xb)[i] = o;
  }
}

// ---------- convert + transpose W1[e][d][f] -> w1t[e][f][d] bf16 ----------
__global__ void cvt_w1(const float* __restrict__ W1, u16* __restrict__ w1t) {
  __shared__ float tile[64][65];
  int e = blockIdx.z;
  int d0 = blockIdx.y * 64, f0 = blockIdx.x * 64;
  int tid = threadIdx.x;
  int r = tid >> 2, cs = (tid & 3) * 16;
  const float* src = W1 + ((size_t)e * D_ + d0) * F_ + f0;
  #pragma unroll
  for (int j = 0; j < 4; ++j) {
    float4 v = *(const float4*)&src[(size_t)r * F_ + cs + j*4];
    tile[r][cs + j*4 + 0] = v.x;
    tile[r][cs + j*4 + 1] = v.y;
    tile[r][cs + j*4 + 2] = v.z;
    tile[r][cs + j*4 + 3] = v.w;
  }
  __syncthreads();
  u32 vals[8];
  #pragma unroll
  for (int j = 0; j < 8; ++j) {
    u32 lo = f2bf(tile[cs + 2*j][r]);
    u32 hi = f2bf(tile[cs + 2*j + 1][r]);
    vals[j] = lo | (hi << 16);
  }
  uint4 A = {vals[0], vals[1], vals[2], vals[3]};
  uint4 Bv = {vals[4], vals[5], vals[6], vals[7]};
  uint4* dst = (uint4*)(w1t + ((size_t)e * F_ + f0 + r) * D_ + d0 + cs);
  dst[0] = A;
  dst[1] = Bv;
}

// ---------- router: fp32 logits, top-2, softmax -> dense gates [T][E] ----------
__global__ void router(const float* __restrict__ x, const float* __restrict__ Wg,
                       const float* __restrict__ bg, float* __restrict__ gdense) {
  int wave = (blockIdx.x * blockDim.x + threadIdx.x) >> 6;
  int lane = threadIdx.x & 63;
  if (wave >= T_) return;
  const float* xr = x + (size_t)wave * D_;
  float acc[8] = {0,0,0,0,0,0,0,0};
  for (int i = 0; i < D_/64; ++i) {
    int d = i*64 + lane;
    float xv = xr[d];
    const float4* wr = (const float4*)(Wg + (size_t)d * E_);
    float4 wa = wr[0], wb2 = wr[1];
    acc[0] += xv * wa.x;  acc[1] += xv * wa.y;
    acc[2] += xv * wa.z;  acc[3] += xv * wa.w;
    acc[4] += xv * wb2.x; acc[5] += xv * wb2.y;
    acc[6] += xv * wb2.z; acc[7] += xv * wb2.w;
  }
  #pragma unroll
  for (int e = 0; e < 8; ++e) {
    #pragma unroll
    for (int s = 32; s > 0; s >>= 1) acc[e] += __shfl_xor(acc[e], s);
  }
  if (lane == 0) {
    float v[8];
    #pragma unroll
    for (int e = 0; e < 8; ++e) v[e] = acc[e] + bg[e];
    int i1 = -1, i2 = -1;
    float b1v = -1e30f, b2v = -1e30f;
    #pragma unroll
    for (int e = 0; e < 8; ++e) {
      float vv = v[e];
      if (vv > b1v) { b2v = b1v; i2 = i1; b1v = vv; i1 = e; }
      else if (vv > b2v) { b2v = vv; i2 = e; }
    }
    float e2 = __expf(b2v - b1v);
    float inv = 1.f / (1.f + e2);
    float* gr = gdense + (size_t)wave * E_;
    #pragma unroll
    for (int e = 0; e < 8; ++e) gr[e] = 0.f;
    gr[i1] = inv;
    gr[i2] = e2 * inv;
  }
}

// ---------- compaction: per (b,e) ordered token list, padded to FULL N_ ----------
__global__ void compact(const float* __restrict__ gdense, int* __restrict__ lists,
                        float* __restrict__ glist, int* __restrict__ cntp,
                        float* __restrict__ G) {
  int be = blockIdx.x;
  int b = be >> 3, e = be & 7;
  __shared__ int warp_off[4];
  __shared__ float wsum[4];
  int tid = threadIdx.x;
  int lane = tid & 63, w = tid >> 6;
  int base = 0;
  float gsum = 0.f;
  for (int c = 0; c < N_; c += 256) {
    int t = b * N_ + c + tid;
    float g = gdense[(size_t)t * E_ + e];
    gsum += g;
    bool sel = g > 0.f;
    unsigned long long m = __ballot(sel);
    int my = __popcll(m & ((1ull << lane) - 1ull));
    int wcnt = __popcll(m);
    if (lane == 0) warp_off[w] = wcnt;
    __syncthreads();
    int off = 0;
    for (int i = 0; i < w; ++i) off += warp_off[i];
    int tot = warp_off[0] + warp_off[1] + warp_off[2] + warp_off[3];
    if (sel) {
      int pos = base + off + my;
      lists[be * N_ + pos] = t;
      glist[be * N_ + pos] = g;
    }
    base += tot;
    __syncthreads();
  }
  // pad with dummy token (gate 0) to FULL N_ so gemm1 can over-read safely
  for (int p = base + tid; p < N_; p += 256) {
    lists[be * N_ + p] = b * N_;
    glist[be * N_ + p] = 0.f;
  }
  if (tid == 0) cntp[be] = base;
  #pragma unroll
  for (int s = 32; s > 0; s >>= 1) gsum += __shfl_xor(gsum, s);
  if (lane == 0) wsum[w] = gsum;
  __syncthreads();
  if (tid == 0) G[be] = wsum[0] + wsum[1] + wsum[2] + wsum[3];
}

// ---------- out init with bias-2 term: out[b][h] = sum_e G[b,e]*b2[e][h] ----------
__global__ void init_out(const float* __restrict__ G, const float* __restrict__ b2,
                         float* __restrict__ out) {
  int i = blockIdx.x * 256 + threadIdx.x;
  int b = i >> 10, h = i & 1023;
  float acc = 0.f;
  #pragma unroll
  for (int e = 0; e < 8; ++e) acc += G[b * E_ + e] * b2[e * H_ + h];
  out[i] = acc;
}

// ---------- GEMM1: 256x256 8-phase template (T3+T4+T5) ----------
// Block = (e, ft256, b, chunk256). 512 threads, 8 waves 2Mx4N, wave out 128x64.
// LDS 128KB: 2 buffers x (A 32KB + B 32KB), [k-slice8][row256] layout ->
// conflict-free contiguous ds_read_b128. Per K-tile 4 phases:
// {2x gll16 -> vmcnt(6) at ph0/2 only -> s_barrier -> ds_read -> setprio MFMA}.
__launch_bounds__(512, 1)
__global__ void gemm1(const u16* __restrict__ xb, const u16* __restrict__ w1t,
                      const float* __restrict__ b1, const int* __restrict__ lists,
                      const float* __restrict__ glist, const int* __restrict__ cntp,
                      float* __restrict__ sbuf) {
  int bid = blockIdx.x;
  int e     = bid & 7;          // XCD id == expert
  int idx   = bid >> 3;
  int ft    = idx & 15;         // 0..15 -> 256-wide f tile
  int b     = (idx >> 4) & 7;
  int chunk = idx >> 7;         // 0..7 -> 256-row chunk
  int be = b * 8 + e;
  int cnt = cntp[be];
  if (chunk * 256 >= cnt) return;
  int fbase = ft * 256;

  __shared__ u16 sA[2][16384];   // [buf][k-slice8 * 256rows * 8k] (short8 unit = (ks*256+row))
  __shared__ u16 sB[2][16384];

  int tid  = threadIdx.x;
  int lane = tid & 63;
  int w    = tid >> 6;
  int wm   = w >> 2;            // 0..1 -> rows wm*128
  int wn   = w & 3;             // 0..3 -> f cols wn*64
  int fr   = lane & 15;
  int kq   = lane >> 4;         // 0..3
  int wk   = tid >> 8;          // 0..1: k sub-slice of staging
  int wrow = (w & 3) * 512;     // element base (64 rows * 8 elem)
  int row  = tid & 255;

  int tok = lists[be * N_ + chunk * 256 + row];
  const u16* aSrc = xb + (size_t)tok * D_ + wk * 8;
  const u16* bSrc = w1t + ((size_t)(e * F_ + fbase + row)) * D_ + wk * 8;

  // stage half h (h=0: k 0..32, h=1: k 32..64) of tile t_ into buffer t_&1.
  // dest element = (2j + wk)*2048 + wrow + lane*8, j = 2h or 2h+1 (k-slice pair)
#define STAGE_A(t_, h_) do { u32 sb_ = (t_) & 1; \
    gll16(aSrc + (t_)*64 + (2*(h_))*16,   &sA[sb_][(u32)(4*(h_)     + wk)*2048 + wrow]); \
    gll16(aSrc + (t_)*64 + (2*(h_)+1)*16, &sA[sb_][(u32)(4*(h_) + 2 + wk)*2048 + wrow]); \
  } while (0)
#define STAGE_B(t_, h_) do { u32 sb_ = (t_) & 1; \
    gll16(bSrc + (t_)*64 + (2*(h_))*16,   &sB[sb_][(u32)(4*(h_)     + wk)*2048 + wrow]); \
    gll16(bSrc + (t_)*64 + (2*(h_)+1)*16, &sB[sb_][(u32)(4*(h_) + 2 + wk)*2048 + wrow]); \
  } while (0)

  f32x4 acc[8][4];
  #pragma unroll
  for (int i = 0; i < 8; ++i)
    #pragma unroll
    for (int j = 0; j < 4; ++j) acc[i][j] = (f32x4){0.f, 0.f, 0.f, 0.f};
  short8 a[4], bb[4];

  // prologue: tile 0 fully staged (8 gll16/wave)
  STAGE_A(0, 0); STAGE_B(0, 0); STAGE_A(0, 1); STAGE_B(0, 1);

  const int NK = D_ / 64;   // 16
  for (int t = 0; t < NK; ++t) {
    int bt = t & 1;
    const short8* Ab = (const short8*)&sA[bt][0];
    const short8* Bb = (const short8*)&sB[bt][0];
    bool more = (t + 1 < NK);

    // ---- phase 0: kh=0, mh=0 ----
    if (more) {
      STAGE_A(t + 1, 0);
      asm volatile("s_waitcnt vmcnt(6)" ::: "memory");   // tile-t A01,B01 landed
    } else {
      asm volatile("s_waitcnt vmcnt(4)" ::: "memory");
    }
    __builtin_amdgcn_s_barrier();
    __builtin_amdgcn_sched_barrier(0);
    #pragma unroll
    for (int i = 0; i < 4; ++i) a[i]  = Ab[kq*256 + wm*128 + i*16 + fr];
    #pragma unroll
    for (int j = 0; j < 4; ++j) bb[j] = Bb[kq*256 + wn*64  + j*16 + fr];
    __builtin_amdgcn_s_setprio(1);
    #pragma unroll
    for (int i = 0; i < 4; ++i)
      #pragma unroll
      for (int j = 0; j < 4; ++j)
        acc[i][j] = __builtin_amdgcn_mfma_f32_16x16x32_bf16(a[i], bb[j], acc[i][j], 0, 0, 0);
    __builtin_amdgcn_s_setprio(0);
    __builtin_amdgcn_sched_barrier(0);

    // ---- phase 1: kh=0, mh=1 (B frags reused) ----
    if (more) STAGE_B(t + 1, 0);
    __builtin_amdgcn_s_barrier();
    __builtin_amdgcn_sched_barrier(0);
    #pragma unroll
    for (int i = 0; i < 4; ++i) a[i] = Ab[kq*256 + wm*128 + 64 + i*16 + fr];
    __builtin_amdgcn_s_setprio(1);
    #pragma unroll
    for (int i = 0; i < 4; ++i)
      #pragma unroll
      for (int j = 0; j < 4; ++j)
        acc[4+i][j] = __builtin_amdgcn_mfma_f32_16x16x32_bf16(a[i], bb[j], acc[4+i][j], 0, 0, 0);
    __builtin_amdgcn_s_setprio(0);
    __builtin_amdgcn_sched_barrier(0);

    // ---- phase 2: kh=1, mh=0 ----
    if (more) {
      STAGE_A(t + 1, 1);
      asm volatile("s_waitcnt vmcnt(6)" ::: "memory");   // tile-t A23,B23 landed
    } else {
      asm volatile("s_waitcnt vmcnt(0)" ::: "memory");
    }
    __builtin_amdgcn_s_barrier();
    __builtin_amdgcn_sched_barrier(0);
    #pragma unroll
    for (int i = 0; i < 4; ++i) a[i]  = Ab[(4+kq)*256 + wm*128 + i*16 + fr];
    #pragma unroll
    for (int j = 0; j < 4; ++j) bb[j] = Bb[(4+kq)*256 + wn*64  + j*16 + fr];
    __builtin_amdgcn_s_setprio(1);
    #pragma unroll
    for (int i = 0; i < 4; ++i)
      #pragma unroll
      for (int j = 0; j < 4; ++j)
        acc[i][j] = __builtin_amdgcn_mfma_f32_16x16x32_bf16(a[i], bb[j], acc[i][j], 0, 0, 0);
    __builtin_amdgcn_s_setprio(0);
    __builtin_amdgcn_sched_barrier(0);

    // ---- phase 3: kh=1, mh=1 ----
    if (more) STAGE_B(t + 1, 1);
    __builtin_amdgcn_s_barrier();
    __builtin_amdgcn_sched_barrier(0);
    #pragma unroll
    for (int i = 0; i < 4; ++i) a[i] = Ab[(4+kq)*256 + wm*128 + 64 + i*16 + fr];
    __builtin_amdgcn_s_setprio(1);
    #pragma unroll
    for (int i = 0; i < 4; ++i)
      #pragma unroll
      for (int j = 0; j < 4; ++j)
        acc[4+i][j] = __builtin_amdgcn_mfma_f32_16x16x32_bf16(a[i], bb[j], acc[4+i][j], 0, 0, 0);
    __builtin_amdgcn_s_setprio(0);
    __builtin_amdgcn_sched_barrier(0);
  }
#undef STAGE_A
#undef STAGE_B

  // epilogue: relu(acc + b1) * gate, column-sum over the chunk's 256 rows
  float b1f[4];
  #pragma unroll
  for (int j = 0; j < 4; ++j)
    b1f[j] = b1[e * F_ + fbase + wn * 64 + j * 16 + fr];
  const float* gRow = glist + be * N_ + chunk * 256;
  float osum[4] = {0.f, 0.f, 0.f, 0.f};
  #pragma unroll
  for (int i = 0; i < 8; ++i) {
    float4 g = *(const float4*)&gRow[wm * 128 + i * 16 + kq * 4];
    #pragma unroll
    for (int j = 0; j < 4; ++j) {
      osum[j] += fmaxf(acc[i][j][0] + b1f[j], 0.f) * g.x
               + fmaxf(acc[i][j][1] + b1f[j], 0.f) * g.y
               + fmaxf(acc[i][j][2] + b1f[j], 0.f) * g.z
               + fmaxf(acc[i][j][3] + b1f[j], 0.f) * g.w;
    }
  }
  #pragma unroll
  for (int j = 0; j < 4; ++j) {
    osum[j] += __shfl_xor(osum[j], 16);
    osum[j] += __shfl_xor(osum[j], 32);
  }
  float* sRed = (float*)&sA[0][0];
  __syncthreads();
  if (wm == 0 && lane < 16) {
    #pragma unroll
    for (int j = 0; j < 4; ++j)
      sRed[wn * 64 + j * 16 + lane] = osum[j];
  }
  __syncthreads();
  if (wm == 1 && lane < 16) {
    #pragma unroll
    for (int j = 0; j < 4; ++j) {
      int fc = wn * 64 + j * 16 + lane;
      atomicAdd(&sbuf[(size_t)be * F_ + fbase + fc], sRed[fc] + osum[j]);
    }
  }
}

// ---------- GEMM2: out[b][h] += sum_f s[b,e,f] * W2[e][f][h] (memory-bound) ----------
__global__ void gemm2(const float* __restrict__ sbuf, const float* __restrict__ W2,
                      float* __restrict__ out) {
  int fc = blockIdx.x;   // 16 chunks of 256 f
  int ht = blockIdx.y;   // 4 tiles of 256 h
  int e  = blockIdx.z;   // 8 experts
  __shared__ float sS[8][256];
  int tid = threadIdx.x;
  #pragma unroll
  for (int b = 0; b < 8; ++b)
    sS[b][tid] = sbuf[((size_t)(b * E_ + e)) * F_ + fc * 256 + tid];
  __syncthreads();
  int h = ht * 256 + tid;
  float acc[8] = {0,0,0,0,0,0,0,0};
  const float* w2p = W2 + (size_t)e * F_ * H_ + (size_t)(fc * 256) * H_ + h;
  for (int f = 0; f < 256; ++f) {
    float wv = w2p[(size_t)f * H_];
    #pragma unroll
    for (int b = 0; b < 8; ++b) acc[b] += sS[b][f] * wv;
  }
  #pragma unroll
  for (int b = 0; b < 8; ++b) atomicAdd(&out[b * H_ + h], acc[b]);
}

extern "C" void kernel_launch(void* const* d_in, const int* in_sizes, int n_in,
                              void* d_out, int out_size, void* d_ws, size_t ws_size,
                              hipStream_t stream) {
  const float* x  = (const float*)d_in[0];
  const float* Wg = (const float*)d_in[1];
  const float* bg = (const float*)d_in[2];
  const float* W1 = (const float*)d_in[3];
  const float* b1 = (const float*)d_in[4];
  const float* W2 = (const float*)d_in[5];
  const float* b2 = (const float*)d_in[6];
  float* out = (float*)d_out;

  char* ws = (char*)d_ws;
  u16*   xb     = (u16*)(ws);
  u16*   w1t    = (u16*)(ws + 33554432);
  float* gdense = (float*)(ws + 100663296);
  int*   lists  = (int*)(ws + 101187584);
  float* glist  = (float*)(ws + 101711872);
  int*   cntp   = (int*)(ws + 102236160);
  float* G      = (float*)(ws + 102236416);
  float* sbuf   = (float*)(ws + 102236672);

  hipMemsetAsync(sbuf, 0, (size_t)64 * F_ * sizeof(float), stream);
  cvt_x<<<8192, 256, 0, stream>>>(x, xb);
  cvt_w1<<<dim3(F_/64, D_/64, E_), 256, 0, stream>>>(W1, w1t);
  router<<<T_/4, 256, 0, stream>>>(x, Wg, bg, gdense);
  compact<<<64, 256, 0, stream>>>(gdense, lists, glist, cntp, G);
  init_out<<<(B_*H_)/256, 256, 0, stream>>>(G, b2, out);
  gemm1<<<8192, 512, 0, stream>>>(xb, w1t, b1, lists, glist, cntp, sbuf);
  gemm2<<<dim3(16, 4, 8), 256, 0, stream>>>(sbuf, W2, out);
}